// Round 4
// baseline (7500.029 us; speedup 1.0000x reference)
//
#include <hip/hip_runtime.h>
#include <stdint.h>

// EncDecAD: encoder LSTM (256) -> Linear -> self-feeding decoder LSTM (256).
// Persistent: 256 blocks (1/CU), 16 groups x 16 blocks; group = 32 batch rows,
// block = 16 h-cols. Weights resident as MFMA B-frags in VGPRs (R3 compute).
// R7: TAG-IN-DATA exchange replaces the {store -> vmcnt drain -> flag ->
// poll -> load} chain (R3) with a single {store -> consumer-load-sees-it}
// link. h is exchanged as 8B atomics: (step_tag<<32)|(2x bf16). Consumers
// poll the data itself, retrying until every tag matches the step sequence
// number; per-8B atomicity delivers tag+payload together, so NO drains, NO
// flags, NO fences. 2-slot ping-pong (slot = seq&1) is race-free: a slot is
// rewritten only after a full all-to-all exchange separates reuses, and the
// tag-poll also provides the intra-block ordering the old flag poll gave
// (a wave passes ld_tile(s) only after all 4 block waves issued tag-s
// stores, which follow their hsh reads). osh/out values are read to regs
// BEFORE the tagged store (read-before-publish). Retries are budget-bounded
// (fail-wrong, never hang). Workspace: 2 x 512KB tagged slots (ws zeroed by
// harness reset each iteration -> tags start at 0, same assumption as R3's
// flags). Numerics bitwise-identical to R3.

#define H_ 256
#define B_ 512
#define T_ 256

typedef short short8 __attribute__((ext_vector_type(8)));
typedef float f32x4 __attribute__((ext_vector_type(4)));

__device__ __forceinline__ short f2bf(float f) {
  union { float f; uint32_t u; } v; v.f = f;
  uint32_t r = (v.u + 0x7FFFu + ((v.u >> 16) & 1u)) >> 16;  // RNE
  return (short)(uint16_t)r;
}

__device__ __forceinline__ short8 load8f_bf(const float* __restrict__ p) {
  const float4 a = *(const float4*)p;
  const float4 b = *(const float4*)(p + 4);
  short8 r;
  r[0]=f2bf(a.x); r[1]=f2bf(a.y); r[2]=f2bf(a.z); r[3]=f2bf(a.w);
  r[4]=f2bf(b.x); r[5]=f2bf(b.y); r[6]=f2bf(b.z); r[7]=f2bf(b.w);
  return r;
}

__device__ __forceinline__ short8 load8f_bf_sum(const float* __restrict__ p,
                                                const float* __restrict__ q) {
  const float4 a = *(const float4*)p, b = *(const float4*)(p + 4);
  const float4 c = *(const float4*)q, d = *(const float4*)(q + 4);
  short8 r;
  r[0]=f2bf(a.x+c.x); r[1]=f2bf(a.y+c.y); r[2]=f2bf(a.z+c.z); r[3]=f2bf(a.w+c.w);
  r[4]=f2bf(b.x+d.x); r[5]=f2bf(b.y+d.y); r[6]=f2bf(b.z+d.z); r[7]=f2bf(b.w+d.w);
  return r;
}

__device__ __forceinline__ float sigm(float x)  { return 1.0f / (1.0f + __expf(-x)); }
__device__ __forceinline__ float tanh_(float x) { return 1.0f - 2.0f / (1.0f + __expf(2.0f * x)); }

__global__ __launch_bounds__(256, 1) void encdec_kernel(
    const float* __restrict__ x,
    const float* __restrict__ Wih1, const float* __restrict__ Whh1,
    const float* __restrict__ bih1, const float* __restrict__ bhh1,
    const float* __restrict__ W1,   const float* __restrict__ b1,
    const float* __restrict__ Wih2, const float* __restrict__ Whh2,
    const float* __restrict__ bih2, const float* __restrict__ bhh2,
    float* __restrict__ out,
    uint64_t* __restrict__ s0, uint64_t* __restrict__ s1)
{
  __shared__ uint16_t hsh[32][16];  // block's h tile (b_loc x col16), bf16
  __shared__ float    osh[32][16];  // block's out tile, fp32 (decoder)

  const int tid = threadIdx.x;
  const int l   = tid & 63;
  const int w   = tid >> 6;
  const int blk = blockIdx.x;
  const int gid = (blk & 7) | ((blk >> 7) << 3);   // group: same blk%8 (XCD locality)
  const int mid = (blk >> 3) & 15;
  const int bg  = gid * 32;

  const int nl   = l & 15;
  const int kc   = l >> 4;
  const int gate = nl >> 2;
  const int cm   = nl & 3;
  const int colg = mid * 16 + w * 4 + cm;
  const int grow = gate * H_ + colg;

  uint64_t* slot[2] = { s0, s1 };   // tagged h: u64[B][H/2], slot = seq&1
  int budget = 1 << 20;             // global retry budget -> fail-wrong, no hang

  // ---- tagged tile load: poll data until all 64 u64 tags == tag ----
  auto ld_tile = [&](const uint64_t* s, uint32_t tag, short8 (&hA)[2][8]) {
    uint64_t raw[2][8][4];
    for (;;) {
#pragma unroll
      for (int mt = 0; mt < 2; ++mt) {
        const uint64_t* rp = s + (size_t)(bg + mt * 16 + nl) * (H_ / 2) + kc * 4;
#pragma unroll
        for (int kt = 0; kt < 8; ++kt)
#pragma unroll
          for (int i = 0; i < 4; ++i)
            raw[mt][kt][i] = __hip_atomic_load(rp + kt * 16 + i,
                                               __ATOMIC_RELAXED, __HIP_MEMORY_SCOPE_AGENT);
      }
      uint32_t bad = 0;
#pragma unroll
      for (int mt = 0; mt < 2; ++mt)
#pragma unroll
        for (int kt = 0; kt < 8; ++kt)
#pragma unroll
          for (int i = 0; i < 4; ++i)
            bad |= ((uint32_t)(raw[mt][kt][i] >> 32)) ^ tag;
      if (__all(bad == 0) || --budget < 0) break;
    }
#pragma unroll
    for (int mt = 0; mt < 2; ++mt)
#pragma unroll
      for (int kt = 0; kt < 8; ++kt) {
        union { uint32_t d[4]; short8 v; } u;
#pragma unroll
        for (int i = 0; i < 4; ++i) u.d[i] = (uint32_t)raw[mt][kt][i];
        hA[mt][kt] = u.v;
      }
  };

  const int gb = tid >> 3;          // gather: b_loc 0..31
  const int gc = tid & 7;           // u64 (2-col) chunk within block's 16 cols

  // publish block's h tile from hsh as tagged u64s (reads hsh, then stores)
  auto stg = [&](uint64_t* s, uint32_t tag) {
    uint32_t pay = (uint32_t)hsh[gb][gc * 2] | ((uint32_t)hsh[gb][gc * 2 + 1] << 16);
    __hip_atomic_store(s + (size_t)(bg + gb) * (H_ / 2) + mid * 8 + gc,
                       ((uint64_t)tag << 32) | pay,
                       __ATOMIC_RELAXED, __HIP_MEMORY_SCOPE_AGENT);
  };
  auto ldsbar = [&]() {
    asm volatile("s_waitcnt lgkmcnt(0)\n\ts_barrier" ::: "memory");
  };

  // ---- encoder weight fragments (B-operand: lane = W[n=nl][k=kc*8+j]) ----
  short8 fwa[8], fwb[8];
#pragma unroll
  for (int kt = 0; kt < 8; ++kt) {
    fwa[kt] = load8f_bf(Wih1 + (size_t)grow * H_ + kt * 32 + kc * 8);
    fwb[kt] = load8f_bf(Whh1 + (size_t)grow * H_ + kt * 32 + kc * 8);
  }
  float bias = bih1[grow] + bhh1[grow];

  float cst[2][4];
#pragma unroll
  for (int mt = 0; mt < 2; ++mt)
#pragma unroll
    for (int r = 0; r < 4; ++r) cst[mt][r] = 0.0f;

  // gate math + LDS gather-write (hn only for r==gate; each (mt,kc,gate,cm) unique)
  auto epi = [&](const f32x4* acc, float bias_, bool wout) {
    const int rb = (l & 48) | cm;
#pragma unroll
    for (int mt = 0; mt < 2; ++mt) {
      float hn = 0.f;
#pragma unroll
      for (int r = 0; r < 4; ++r) {
        float z = acc[mt][r] + bias_;
        float a = (gate == 2) ? tanh_(z) : sigm(z);
        float ti = __shfl(a, rb,      64);
        float tf = __shfl(a, rb | 4,  64);
        float tg = __shfl(a, rb | 8,  64);
        float to = __shfl(a, rb | 12, 64);
        float cn = tf * cst[mt][r] + ti * tg;
        cst[mt][r] = cn;
        if (r == gate) hn = to * tanh_(cn);
      }
      hsh[mt * 16 + kc * 4 + gate][w * 4 + cm] = (uint16_t)f2bf(hn);
      if (wout) osh[mt * 16 + kc * 4 + gate][w * 4 + cm] = hn;
    }
  };

  // x-part MFMAs for step t (independent of h) -> overlaps peers' store flight
  f32x4 accN[2];
  auto xmfma = [&](int t) {
#pragma unroll
    for (int mt = 0; mt < 2; ++mt) {
      f32x4 a = {0.f, 0.f, 0.f, 0.f};
      const float* xr = x + ((size_t)(bg + mt * 16 + nl) * T_ + t) * H_ + kc * 8;
#pragma unroll
      for (int kt = 0; kt < 8; ++kt) {
        short8 af = load8f_bf(xr + kt * 32);
        a = __builtin_amdgcn_mfma_f32_16x16x32_bf16(af, fwa[kt], a, 0, 0, 0);
      }
      accN[mt] = a;
    }
  };
  xmfma(0);

  // ---------------- encoder: step t consumes seq=t, produces seq=t+1 ----------------
  for (int t = 0; t < T_; ++t) {
    f32x4 acc[2] = { accN[0], accN[1] };
    if (t > 0) {
      short8 hA[2][8];
      ld_tile(slot[t & 1], (uint32_t)t, hA);
#pragma unroll
      for (int mt = 0; mt < 2; ++mt)
#pragma unroll
        for (int kt = 0; kt < 8; ++kt)
          acc[mt] = __builtin_amdgcn_mfma_f32_16x16x32_bf16(hA[mt][kt], fwb[kt], acc[mt], 0, 0, 0);
    }
    epi(acc, bias, false);
    ldsbar();
    stg(slot[(t + 1) & 1], (uint32_t)(t + 1));
    if (t + 1 < T_) xmfma(t + 1);   // overlapped with peers' store flight
  }

  // ---------------- x_end = h1 @ W1.T + b1 (h1 = seq 256, slot0) ----------------
  short8 h1f[2][8];
  ld_tile(slot[0], 256u, h1f);      // kept live: reused as decoder-t0 B operand
  {
    const int xcol = mid * 16 + nl;
    short8 fw1[8];
#pragma unroll
    for (int kt = 0; kt < 8; ++kt)
      fw1[kt] = load8f_bf(W1 + (size_t)xcol * H_ + kt * 32 + kc * 8);
    f32x4 acc[2] = { {0.f,0.f,0.f,0.f}, {0.f,0.f,0.f,0.f} };
#pragma unroll
    for (int mt = 0; mt < 2; ++mt)
#pragma unroll
      for (int kt = 0; kt < 8; ++kt)
        acc[mt] = __builtin_amdgcn_mfma_f32_16x16x32_bf16(h1f[mt][kt], fw1[kt], acc[mt], 0, 0, 0);
    float bb = b1[xcol];
    if (w == 0) {  // one wave publishes x_end as tagged u64s (seq 257 -> slot1)
#pragma unroll
      for (int mt = 0; mt < 2; ++mt)
#pragma unroll
        for (int r = 0; r < 4; ++r) {
          float me = acc[mt][r] + bb;
          float nb = __shfl(me, l ^ 1, 64);
          if (!(nl & 1)) {
            uint32_t pay = (uint32_t)(uint16_t)f2bf(me) |
                           ((uint32_t)(uint16_t)f2bf(nb) << 16);
            __hip_atomic_store(slot[1] + (size_t)(bg + mt * 16 + kc * 4 + r) * (H_ / 2)
                                       + mid * 8 + (nl >> 1),
                               ((uint64_t)257u << 32) | pay,
                               __ATOMIC_RELAXED, __HIP_MEMORY_SCOPE_AGENT);
          }
        }
    }
  }

  // decoder weight prep in the flight window
  short8 fwa2[8], fwb2[8], fws[8];
#pragma unroll
  for (int kt = 0; kt < 8; ++kt) {
    const float* pa = Wih2 + (size_t)grow * H_ + kt * 32 + kc * 8;
    const float* pb = Whh2 + (size_t)grow * H_ + kt * 32 + kc * 8;
    fwa2[kt] = load8f_bf(pa);
    fwb2[kt] = load8f_bf(pb);
    fws[kt]  = load8f_bf_sum(pa, pb);   // bf16(Wih2+Whh2), summed in fp32
  }
  bias = bih2[grow] + bhh2[grow];

  // ---------------- decoder t=0 (x_end seq 257 w/ fwa2, h1 w/ fwb2) ----------------
  {
    short8 xeF[2][8];
    ld_tile(slot[1], 257u, xeF);
    f32x4 acc[2] = { {0.f,0.f,0.f,0.f}, {0.f,0.f,0.f,0.f} };
#pragma unroll
    for (int mt = 0; mt < 2; ++mt)
#pragma unroll
      for (int kt = 0; kt < 8; ++kt) {
        acc[mt] = __builtin_amdgcn_mfma_f32_16x16x32_bf16(xeF[mt][kt], fwa2[kt], acc[mt], 0, 0, 0);
        acc[mt] = __builtin_amdgcn_mfma_f32_16x16x32_bf16(h1f[mt][kt], fwb2[kt], acc[mt], 0, 0, 0);
      }
    epi(acc, bias, true);
    ldsbar();
    uint64_t ov = *(const uint64_t*)&osh[gb][gc * 2];   // read BEFORE publish
    stg(slot[0], 258u);
    *(uint64_t*)&out[((size_t)(bg + gb) * T_ + (T_ - 2)) * H_ + mid * 16 + gc * 2] = ov;
  }

  // ---------------- decoder t>=1: consumes seq 257+t, produces 258+t ----------------
  for (int t = 1; t < T_; ++t) {
    short8 hA[2][8];
    ld_tile(slot[(257 + t) & 1], (uint32_t)(257 + t), hA);
    f32x4 acc[2] = { {0.f,0.f,0.f,0.f}, {0.f,0.f,0.f,0.f} };
#pragma unroll
    for (int mt = 0; mt < 2; ++mt)
#pragma unroll
      for (int kt = 0; kt < 8; ++kt)
        acc[mt] = __builtin_amdgcn_mfma_f32_16x16x32_bf16(hA[mt][kt], fws[kt], acc[mt], 0, 0, 0);
    epi(acc, bias, true);
    ldsbar();
    const int j = (t == T_ - 1) ? (T_ - 1) : (T_ - 2 - t);
    uint64_t ov = *(const uint64_t*)&osh[gb][gc * 2];   // read BEFORE publish
    if (t + 1 < T_) stg(slot[(258 + t) & 1], (uint32_t)(258 + t));
    *(uint64_t*)&out[((size_t)(bg + gb) * T_ + j) * H_ + mid * 16 + gc * 2] = ov;
  }
}

extern "C" void kernel_launch(void* const* d_in, const int* in_sizes, int n_in,
                              void* d_out, int out_size, void* d_ws, size_t ws_size,
                              hipStream_t stream) {
  const float* x    = (const float*)d_in[0];
  const float* Wih1 = (const float*)d_in[1];
  const float* Whh1 = (const float*)d_in[2];
  const float* bih1 = (const float*)d_in[3];
  const float* bhh1 = (const float*)d_in[4];
  const float* W1   = (const float*)d_in[5];
  const float* b1   = (const float*)d_in[6];
  const float* Wih2 = (const float*)d_in[7];
  const float* Whh2 = (const float*)d_in[8];
  const float* bih2 = (const float*)d_in[9];
  const float* bhh2 = (const float*)d_in[10];
  float* out = (float*)d_out;

  uint64_t* s0 = (uint64_t*)d_ws;                       // tagged slot0: 512 KiB
  uint64_t* s1 = s0 + (size_t)B_ * (H_ / 2);            // tagged slot1: 512 KiB

  hipLaunchKernelGGL(encdec_kernel, dim3(256), dim3(256), 0, stream,
                     x, Wih1, Whh1, bih1, bhh1, W1, b1, Wih2, Whh2, bih2, bhh2,
                     out, s0, s1);
}

// Round 5
// 5708.111 us; speedup vs baseline: 1.3139x; 1.3139x over previous
//
#include <hip/hip_runtime.h>
#include <stdint.h>

// EncDecAD: encoder LSTM (256) -> Linear -> self-feeding decoder LSTM (256).
// Persistent: 256 blocks (1/CU), 16 groups x 16 blocks; group = 32 batch rows,
// block = 16 h-cols. Weights resident as MFMA B-frags in VGPRs.
// R8 = R3 + CHEAP SYNC ONLY (one variable). Probe series showed step time is
// set by POLL TRAFFIC at the coherent point, not data volume: R3 polls gather
// 64 distinct 32B sectors per wave-iteration (~1024 waves -> standing flood
// that queues ahead of the h exchange). R8:
//  - ONE flag per block per step, 16 flags/group packed in one 64B line
//    (2 sectors). Poll iteration = flags[l&15]: 32x cheaper than R3.
//  - Producer: gather-store -> vmcnt(0) -> __syncthreads -> tid0 stores the
//    block flag (barrier aggregates the 4 waves' drains; off the MALL).
// Data path / compute / slot ping-pong / numerics: bitwise-identical to R3.

#define H_ 256
#define B_ 512
#define T_ 256

typedef short short8 __attribute__((ext_vector_type(8)));
typedef float f32x4 __attribute__((ext_vector_type(4)));

__device__ __forceinline__ short f2bf(float f) {
  union { float f; uint32_t u; } v; v.f = f;
  uint32_t r = (v.u + 0x7FFFu + ((v.u >> 16) & 1u)) >> 16;  // RNE
  return (short)(uint16_t)r;
}

__device__ __forceinline__ short8 load8f_bf(const float* __restrict__ p) {
  const float4 a = *(const float4*)p;
  const float4 b = *(const float4*)(p + 4);
  short8 r;
  r[0]=f2bf(a.x); r[1]=f2bf(a.y); r[2]=f2bf(a.z); r[3]=f2bf(a.w);
  r[4]=f2bf(b.x); r[5]=f2bf(b.y); r[6]=f2bf(b.z); r[7]=f2bf(b.w);
  return r;
}

__device__ __forceinline__ short8 load8f_bf_sum(const float* __restrict__ p,
                                                const float* __restrict__ q) {
  const float4 a = *(const float4*)p, b = *(const float4*)(p + 4);
  const float4 c = *(const float4*)q, d = *(const float4*)(q + 4);
  short8 r;
  r[0]=f2bf(a.x+c.x); r[1]=f2bf(a.y+c.y); r[2]=f2bf(a.z+c.z); r[3]=f2bf(a.w+c.w);
  r[4]=f2bf(b.x+d.x); r[5]=f2bf(b.y+d.y); r[6]=f2bf(b.z+d.z); r[7]=f2bf(b.w+d.w);
  return r;
}

__device__ __forceinline__ short8 coh_load16(const uint16_t* p) {
  union { uint64_t u[2]; short8 v; } r;
  const uint64_t* q = (const uint64_t*)p;
  r.u[0] = __hip_atomic_load(q,     __ATOMIC_RELAXED, __HIP_MEMORY_SCOPE_AGENT);
  r.u[1] = __hip_atomic_load(q + 1, __ATOMIC_RELAXED, __HIP_MEMORY_SCOPE_AGENT);
  return r.v;
}

__device__ __forceinline__ float sigm(float x)  { return 1.0f / (1.0f + __expf(-x)); }
__device__ __forceinline__ float tanh_(float x) { return 1.0f - 2.0f / (1.0f + __expf(2.0f * x)); }

__global__ __launch_bounds__(256, 1) void encdec_kernel(
    const float* __restrict__ x,
    const float* __restrict__ Wih1, const float* __restrict__ Whh1,
    const float* __restrict__ bih1, const float* __restrict__ bhh1,
    const float* __restrict__ W1,   const float* __restrict__ b1,
    const float* __restrict__ Wih2, const float* __restrict__ Whh2,
    const float* __restrict__ bih2, const float* __restrict__ bhh2,
    float* __restrict__ out,
    uint32_t* __restrict__ bar,
    uint16_t* __restrict__ hbuf)
{
  __shared__ uint16_t hsh[32][16];  // block's h tile (b_loc x col16), bf16
  __shared__ float    osh[32][16];  // block's out tile, fp32 (decoder)

  const int tid = threadIdx.x;
  const int l   = tid & 63;
  const int w   = tid >> 6;
  const int blk = blockIdx.x;
  const int gid = (blk & 7) | ((blk >> 7) << 3);   // group: same blk%8 (XCD locality)
  const int mid = (blk >> 3) & 15;
  const int bg  = gid * 32;
  const int c0  = mid * 16 + w * 4;

  const int nl   = l & 15;
  const int kc   = l >> 4;
  const int gate = nl >> 2;
  const int cm   = nl & 3;
  const int colg = c0 + cm;
  const int grow = gate * H_ + colg;

  // flags: 16 per group (one per block), PACKED in one 64B line (2 sectors).
  uint32_t* flags = bar + (size_t)gid * 512;

  uint16_t* slot0 = hbuf;
  uint16_t* slot1 = hbuf + (size_t)B_ * H_;
  uint16_t* slot2 = hbuf + (size_t)2 * B_ * H_;

  auto arrive = [&](int target) {
    asm volatile("s_waitcnt vmcnt(0)" ::: "memory");   // my coherent stores drained
    __syncthreads();                                   // all 4 waves drained
    if (tid == 0)
      __hip_atomic_store(&flags[mid], (uint32_t)target,
                         __ATOMIC_RELAXED, __HIP_MEMORY_SCOPE_AGENT);
  };
  auto poll = [&](int target) {
    int g = 0;
    while ((int)__hip_atomic_load(&flags[l & 15], __ATOMIC_RELAXED,
                                  __HIP_MEMORY_SCOPE_AGENT) < target) {
      __builtin_amdgcn_s_sleep(1);
      if (++g > 2000000) break;  // fail-wrong, not hang
    }
    asm volatile("" ::: "memory");
  };
  auto ldsbar = [&]() {
    asm volatile("s_waitcnt lgkmcnt(0)\n\ts_barrier" ::: "memory");
  };

  // ---- encoder weight fragments (B-operand: lane = W[n=nl][k=kc*8+j]) ----
  short8 fwa[8], fwb[8];
#pragma unroll
  for (int kt = 0; kt < 8; ++kt) {
    fwa[kt] = load8f_bf(Wih1 + (size_t)grow * H_ + kt * 32 + kc * 8);
    fwb[kt] = load8f_bf(Whh1 + (size_t)grow * H_ + kt * 32 + kc * 8);
  }
  float bias = bih1[grow] + bhh1[grow];

  float cst[2][4];
#pragma unroll
  for (int mt = 0; mt < 2; ++mt)
#pragma unroll
    for (int r = 0; r < 4; ++r) cst[mt][r] = 0.0f;

  // gate math + LDS gather-write (hn only for r==gate; each (mt,kc,gate,cm) is unique)
  auto epi = [&](const f32x4* acc, float bias_, bool wout) {
    const int rb = (l & 48) | cm;
#pragma unroll
    for (int mt = 0; mt < 2; ++mt) {
      float hn = 0.f;
#pragma unroll
      for (int r = 0; r < 4; ++r) {
        float z = acc[mt][r] + bias_;
        float a = (gate == 2) ? tanh_(z) : sigm(z);
        float ti = __shfl(a, rb,      64);
        float tf = __shfl(a, rb | 4,  64);
        float tg = __shfl(a, rb | 8,  64);
        float to = __shfl(a, rb | 12, 64);
        float cn = tf * cst[mt][r] + ti * tg;
        cst[mt][r] = cn;
        if (r == gate) hn = to * tanh_(cn);
      }
      hsh[mt * 16 + kc * 4 + gate][w * 4 + cm] = (uint16_t)f2bf(hn);
      if (wout) osh[mt * 16 + kc * 4 + gate][w * 4 + cm] = hn;
    }
  };

  const int gb = tid >> 3;          // gather: b_loc 0..31
  const int gc = tid & 7;           // 4B chunk within the 32B row-chunk

  // x-part MFMAs for step t (independent of h) -> runs post-flag, pre-poll
  f32x4 accN[2];
  auto xmfma = [&](int t) {
#pragma unroll
    for (int mt = 0; mt < 2; ++mt) {
      f32x4 a = {0.f, 0.f, 0.f, 0.f};
      const float* xr = x + ((size_t)(bg + mt * 16 + nl) * T_ + t) * H_ + kc * 8;
#pragma unroll
      for (int kt = 0; kt < 8; ++kt) {
        short8 af = load8f_bf(xr + kt * 32);
        a = __builtin_amdgcn_mfma_f32_16x16x32_bf16(af, fwa[kt], a, 0, 0, 0);
      }
      accN[mt] = a;
    }
  };
  xmfma(0);

  // ---------------- encoder ----------------
  for (int t = 0; t < T_; ++t) {
    f32x4 acc[2] = { accN[0], accN[1] };
    if (t > 0) {
      poll(t);
      const uint16_t* hs = (t & 1) ? slot1 : slot0;
      short8 hA[2][8];
#pragma unroll
      for (int mt = 0; mt < 2; ++mt)
#pragma unroll
        for (int kt = 0; kt < 8; ++kt)
          hA[mt][kt] = coh_load16(hs + (size_t)(bg + mt * 16 + nl) * H_ + kt * 32 + kc * 8);
#pragma unroll
      for (int mt = 0; mt < 2; ++mt)
#pragma unroll
        for (int kt = 0; kt < 8; ++kt)
          acc[mt] = __builtin_amdgcn_mfma_f32_16x16x32_bf16(hA[mt][kt], fwb[kt], acc[mt], 0, 0, 0);
    }
    epi(acc, bias, false);
    ldsbar();
    uint16_t* hw = ((t + 1) & 1) ? slot1 : slot0;
    {
      uint32_t hv = *(const uint32_t*)&hsh[gb][gc * 2];
      __hip_atomic_store((uint32_t*)&hw[(size_t)(bg + gb) * H_ + mid * 16 + gc * 2], hv,
                         __ATOMIC_RELAXED, __HIP_MEMORY_SCOPE_AGENT);
    }
    arrive(t + 1);
    if (t + 1 < T_) xmfma(t + 1);   // overlapped with peers' arrival
  }

  // ---------------- x_end = h1 @ W1.T + b1  (h1 in slot0) ----------------
  poll(T_);
  {
    const int xcol = mid * 16 + nl;
    short8 fw1[8];
#pragma unroll
    for (int kt = 0; kt < 8; ++kt)
      fw1[kt] = load8f_bf(W1 + (size_t)xcol * H_ + kt * 32 + kc * 8);
    f32x4 acc[2] = { {0.f,0.f,0.f,0.f}, {0.f,0.f,0.f,0.f} };
#pragma unroll
    for (int mt = 0; mt < 2; ++mt) {
      const uint16_t* hr = slot0 + (size_t)(bg + mt * 16 + nl) * H_ + kc * 8;
#pragma unroll
      for (int kt = 0; kt < 8; ++kt) {
        short8 af = coh_load16(hr + kt * 32);
        acc[mt] = __builtin_amdgcn_mfma_f32_16x16x32_bf16(af, fw1[kt], acc[mt], 0, 0, 0);
      }
    }
    float bb = b1[xcol];
    if (w == 0) {  // one wave writes x_end (scattered 2B, one-time)
#pragma unroll
      for (int mt = 0; mt < 2; ++mt)
#pragma unroll
        for (int r = 0; r < 4; ++r) {
          int b = bg + mt * 16 + kc * 4 + r;
          __hip_atomic_store(&slot2[(size_t)b * H_ + mid * 16 + nl], (uint16_t)f2bf(acc[mt][r] + bb),
                             __ATOMIC_RELAXED, __HIP_MEMORY_SCOPE_AGENT);
        }
    }
  }
  arrive(T_ + 1);

  // decoder weight prep in the window
  short8 fwa2[8], fwb2[8], fws[8];
#pragma unroll
  for (int kt = 0; kt < 8; ++kt) {
    const float* pa = Wih2 + (size_t)grow * H_ + kt * 32 + kc * 8;
    const float* pb = Whh2 + (size_t)grow * H_ + kt * 32 + kc * 8;
    fwa2[kt] = load8f_bf(pa);
    fwb2[kt] = load8f_bf(pb);
    fws[kt]  = load8f_bf_sum(pa, pb);   // bf16(Wih2+Whh2), summed in fp32
  }
  bias = bih2[grow] + bhh2[grow];
  poll(T_ + 1);

  // ---------------- decoder t=0 (x_end w/ fwa2, h1 w/ fwb2) ----------------
  {
    f32x4 acc[2] = { {0.f,0.f,0.f,0.f}, {0.f,0.f,0.f,0.f} };
    short8 hA[2][8], hB[2][8];
#pragma unroll
    for (int mt = 0; mt < 2; ++mt)
#pragma unroll
      for (int kt = 0; kt < 8; ++kt) {
        const size_t ro = (size_t)(bg + mt * 16 + nl) * H_ + kt * 32 + kc * 8;
        hA[mt][kt] = coh_load16(slot2 + ro);
        hB[mt][kt] = coh_load16(slot0 + ro);
      }
#pragma unroll
    for (int mt = 0; mt < 2; ++mt)
#pragma unroll
      for (int kt = 0; kt < 8; ++kt) {
        acc[mt] = __builtin_amdgcn_mfma_f32_16x16x32_bf16(hA[mt][kt], fwa2[kt], acc[mt], 0, 0, 0);
        acc[mt] = __builtin_amdgcn_mfma_f32_16x16x32_bf16(hB[mt][kt], fwb2[kt], acc[mt], 0, 0, 0);
      }
    epi(acc, bias, true);
    ldsbar();
    uint32_t hv = *(const uint32_t*)&hsh[gb][gc * 2];
    uint64_t ov = *(const uint64_t*)&osh[gb][gc * 2];
    __hip_atomic_store((uint32_t*)&slot1[(size_t)(bg + gb) * H_ + mid * 16 + gc * 2], hv,
                       __ATOMIC_RELAXED, __HIP_MEMORY_SCOPE_AGENT);
    arrive(T_ + 2);
    *(uint64_t*)&out[((size_t)(bg + gb) * T_ + (T_ - 2)) * H_ + mid * 16 + gc * 2] = ov;
  }

  // ---------------- decoder t>=1 (merged weights; x_t == h_{t-1}) ----------------
  for (int t = 1; t < T_; ++t) {
    poll(T_ + 1 + t);
    const uint16_t* hs = (t & 1) ? slot1 : slot0;
    f32x4 acc[2] = { {0.f,0.f,0.f,0.f}, {0.f,0.f,0.f,0.f} };
    short8 hA[2][8];
#pragma unroll
    for (int mt = 0; mt < 2; ++mt)
#pragma unroll
      for (int kt = 0; kt < 8; ++kt)
        hA[mt][kt] = coh_load16(hs + (size_t)(bg + mt * 16 + nl) * H_ + kt * 32 + kc * 8);
#pragma unroll
    for (int mt = 0; mt < 2; ++mt)
#pragma unroll
      for (int kt = 0; kt < 8; ++kt)
        acc[mt] = __builtin_amdgcn_mfma_f32_16x16x32_bf16(hA[mt][kt], fws[kt], acc[mt], 0, 0, 0);

    epi(acc, bias, true);
    ldsbar();
    const int j = (t == T_ - 1) ? (T_ - 1) : (T_ - 2 - t);
    uint32_t hv = *(const uint32_t*)&hsh[gb][gc * 2];
    uint64_t ov = *(const uint64_t*)&osh[gb][gc * 2];
    if (t + 1 < T_) {
      uint16_t* hw = ((t + 1) & 1) ? slot1 : slot0;
      __hip_atomic_store((uint32_t*)&hw[(size_t)(bg + gb) * H_ + mid * 16 + gc * 2], hv,
                         __ATOMIC_RELAXED, __HIP_MEMORY_SCOPE_AGENT);
      arrive(T_ + 2 + t);
    }
    *(uint64_t*)&out[((size_t)(bg + gb) * T_ + j) * H_ + mid * 16 + gc * 2] = ov;
  }
}

extern "C" void kernel_launch(void* const* d_in, const int* in_sizes, int n_in,
                              void* d_out, int out_size, void* d_ws, size_t ws_size,
                              hipStream_t stream) {
  const float* x    = (const float*)d_in[0];
  const float* Wih1 = (const float*)d_in[1];
  const float* Whh1 = (const float*)d_in[2];
  const float* bih1 = (const float*)d_in[3];
  const float* bhh1 = (const float*)d_in[4];
  const float* W1   = (const float*)d_in[5];
  const float* b1   = (const float*)d_in[6];
  const float* Wih2 = (const float*)d_in[7];
  const float* Whh2 = (const float*)d_in[8];
  const float* bih2 = (const float*)d_in[9];
  const float* bhh2 = (const float*)d_in[10];
  float* out = (float*)d_out;

  uint32_t* bar  = (uint32_t*)d_ws;                   // 16 groups x 2 KiB; flags = first 64B of each
  uint16_t* hbuf = (uint16_t*)((char*)d_ws + 32768);  // 3 bf16 (B,H) slots

  hipLaunchKernelGGL(encdec_kernel, dim3(256), dim3(256), 0, stream,
                     x, Wih1, Whh1, bih1, bhh1, W1, b1, Wih2, Whh2, bih2, bhh2,
                     out, bar, hbuf);
}